// Round 13
// baseline (162.584 us; speedup 1.0000x reference)
//
#include <hip/hip_runtime.h>
#include <math.h>

#define S_LEN 2048
#define HID   768
#define NH    12
#define HD    64
#define WIN   128
#define NEGV  (-1e30f)
#define QSCALE 0.1803368801111204f   /* 0.125 * log2(e): scores in log2 domain */
#define MCONST 12.0f                 /* static softmax max (log2 domain) */
#define NROW  49152                  /* B*NH*S = 2*12*2048 */

typedef __attribute__((ext_vector_type(8))) short short8v;
typedef __attribute__((ext_vector_type(16))) float f32x16;
typedef unsigned short u16;

__device__ __forceinline__ u16 f2bf(float f) {
    union { float f; unsigned int u; } c; c.f = f;
    unsigned int u = c.u + 0x7FFFu + ((c.u >> 16) & 1u);
    return (u16)(u >> 16);
}

__device__ __forceinline__ short8v cvt8(float4 a, float4 b) {
    short8v t;
    t[0]=(short)f2bf(a.x); t[1]=(short)f2bf(a.y); t[2]=(short)f2bf(a.z); t[3]=(short)f2bf(a.w);
    t[4]=(short)f2bf(b.x); t[5]=(short)f2bf(b.y); t[6]=(short)f2bf(b.z); t[7]=(short)f2bf(b.w);
    return t;
}

__device__ __forceinline__ unsigned int pk2bf(float a, float b) {
    unsigned int r;
    asm("v_cvt_pk_bf16_f32 %0, %1, %2" : "=v"(r) : "v"(a), "v"(b));
    return r;
}

__device__ __forceinline__ float exp2_fast(float x) {
    float r;
    asm("v_exp_f32 %0, %1" : "=v"(r) : "v"(x));
    return r;
}

__device__ __forceinline__ float bf2f(u16 v) {
    union { float f; unsigned u; } c; c.u = ((unsigned)v) << 16; return c.f;
}

__device__ __forceinline__ void gload_lds16(const void* g, void* l) {
    __builtin_amdgcn_global_load_lds(
        (const __attribute__((address_space(1))) unsigned int*)g,
        (__attribute__((address_space(3))) unsigned int*)l, 16, 0, 0);
}

// C-init builders: S[4m+c] = src[8m + c]
__device__ __forceinline__ void cinit_uni(f32x16& S, const float* src) {
    #pragma unroll
    for (int m = 0; m < 4; m++) {
        float4 f = *(const float4*)(src + 8*m);
        S[4*m+0]=f.x; S[4*m+1]=f.y; S[4*m+2]=f.z; S[4*m+3]=f.w;
    }
}
__device__ __forceinline__ void cinit_mixed(f32x16& S, const float* fa, const float* fb,
                                            int ebase, int gq) {
    #pragma unroll
    for (int m = 0; m < 4; m++) {
        float4 a = *(const float4*)(fa + 8*m);
        float4 b = *(const float4*)(fb + 8*m);
        const int e = ebase - 8*m;
        S[4*m+0] = (gq || (unsigned)(e     + 128) <= 256u) ? a.x : b.x;
        S[4*m+1] = (gq || (unsigned)(e - 1 + 128) <= 256u) ? a.y : b.y;
        S[4*m+2] = (gq || (unsigned)(e - 2 + 128) <= 256u) ? a.z : b.z;
        S[4*m+3] = (gq || (unsigned)(e - 3 + 128) <= 256u) ? a.w : b.w;
    }
}

// ---------------------------------------------------------------------------
// Convert hidden + 4 weights to bf16; y=5: mask addends (with -MCONST folded).
// ---------------------------------------------------------------------------
__global__ __launch_bounds__(256) void convert_inputs(
    const float* __restrict__ hidden, const float* __restrict__ Wq,
    const float* __restrict__ Wk, const float* __restrict__ Wv,
    const float* __restrict__ Wo, const int* __restrict__ amask,
    const int* __restrict__ gmask, u16* __restrict__ hbf,
    u16* __restrict__ w4, float* __restrict__ fAg, float* __restrict__ fBg)
{
    const int y = blockIdx.y;
    if (y == 5) {
        const int idx = (blockIdx.x*256 + threadIdx.x) * 8;
        if (idx >= 2*S_LEN) return;
        #pragma unroll
        for (int u = 0; u < 8; u++) {
            const int am = amask[idx+u], gk = gmask[idx+u];
            fAg[idx+u] = am ? -MCONST : NEGV;
            fBg[idx+u] = (am && gk) ? -MCONST : NEGV;
        }
        return;
    }
    const float* src; u16* dst; int n; float scale = 1.f;
    if (y == 0) { src = hidden; dst = hbf; n = 4096*HID; }
    else {
        src = (y==1) ? Wq : (y==2) ? Wk : (y==3) ? Wv : Wo;
        dst = w4 + (size_t)(y-1)*HID*HID;
        n = HID*HID;
        if (y == 1) scale = QSCALE;
    }
    const int idx = (blockIdx.x*256 + threadIdx.x) * 8;
    if (idx >= n) return;
    float4 f0 = *(const float4*)(src + idx);
    float4 f1 = *(const float4*)(src + idx + 4);
    f0.x*=scale; f0.y*=scale; f0.z*=scale; f0.w*=scale;
    f1.x*=scale; f1.y*=scale; f1.z*=scale; f1.w*=scale;
    *(short8v*)(dst + idx) = cvt8(f0, f1);
}

// ---------------------------------------------------------------------------
// bf16 MFMA GEMM (m97 structure).
// mode 0: z in {0,1,2}: Q,K -> obf + z*NTOK; V (z=2) -> ovt transposed.
// mode 1: Wo; A-operand FUSED-MERGED from split-K partials O0m/O1m/Lpm
//         (replaces the separate attn_merge kernel); out f32 flat (B,S,H).
// ---------------------------------------------------------------------------
typedef __attribute__((ext_vector_type(4))) float float4v;
__global__ __launch_bounds__(256) void gemm_mfma(
    const u16* __restrict__ A, const u16* __restrict__ W4,
    const float* __restrict__ bA, const float* __restrict__ bB,
    const float* __restrict__ bC, u16* __restrict__ obf,
    u16* __restrict__ ovt, float* __restrict__ of32,
    const u16* __restrict__ O0m, const u16* __restrict__ O1m,
    const float* __restrict__ Lpm, int mode)
{
    __shared__ __align__(16) u16 As[128*32];
    __shared__ __align__(16) u16 Bs[128*32];

    const int tid = threadIdx.x;
    const int w = tid >> 6, l = tid & 63;
    const int lx = l & 15, lg = l >> 4;
    const int wr = w >> 1, wc = w & 1;
    const int m0 = blockIdx.x * 128, n0 = blockIdx.y * 128;
    const int z = (mode == 0) ? blockIdx.z : 3;
    const float* bias = (mode == 1) ? bA : (z == 0 ? bA : (z == 1 ? bB : bC));
    const float bscale = (mode == 0 && z == 0) ? QSCALE : 1.0f;
    const u16* Wp = W4 + (size_t)z * (HID*HID);

    float4v acc[4][4];
    const float4v fz = {0.f,0.f,0.f,0.f};
    #pragma unroll
    for (int i = 0; i < 4; i++)
        #pragma unroll
        for (int j = 0; j < 4; j++) acc[i][j] = fz;

    for (int kt = 0; kt < HID/32; kt++) {
        const int k0 = kt * 32;
        __syncthreads();
        #pragma unroll
        for (int rnd = 0; rnd < 2; rnd++) {
            const int ch  = rnd*256 + w*64 + l;
            const int row = ch >> 2, kc = ch & 3;
            if (mode == 1) {
                // fused split-K merge: A[m][kk] = (O0+O1)/(l0+l1), bf16
                const int m  = m0 + row;
                const int kk = k0 + kc*8;
                const int bb2 = m >> 11, s2 = m & 2047;
                const int hh2 = kk >> 6, d2 = kk & 63;
                const size_t rowO = ((size_t)bb2*NH + hh2)*S_LEN + s2;
                uint4 a0 = *(const uint4*)(O0m + rowO*HD + d2);
                uint4 a1 = *(const uint4*)(O1m + rowO*HD + d2);
                const float inv = 1.f / (Lpm[rowO] + Lpm[rowO + NROW]);
                const u16* p0 = (const u16*)&a0;
                const u16* p1 = (const u16*)&a1;
                short8v mm;
                #pragma unroll
                for (int j2 = 0; j2 < 8; j2++)
                    mm[j2] = (short)f2bf((bf2f(p0[j2]) + bf2f(p1[j2])) * inv);
                *(short8v*)(As + (size_t)ch*8) = mm;
            } else {
                gload_lds16(A + (size_t)(m0+row)*HID + k0 + kc*8,
                            As + (size_t)(rnd*256 + w*64)*8);
            }
            gload_lds16(Wp + (size_t)(n0+row)*HID + k0 + kc*8,
                        Bs + (size_t)(rnd*256 + w*64)*8);
        }
        __syncthreads();
        short8v af[4], bfr[4];
        #pragma unroll
        for (int i = 0; i < 4; i++) {
            af[i]  = *(const short8v*)(As + (wr*64 + i*16 + lx)*32 + lg*8);
            bfr[i] = *(const short8v*)(Bs + (wc*64 + i*16 + lx)*32 + lg*8);
        }
        #pragma unroll
        for (int i = 0; i < 4; i++)
            #pragma unroll
            for (int j = 0; j < 4; j++)
                acc[i][j] = __builtin_amdgcn_mfma_f32_16x16x32_bf16(af[i], bfr[j], acc[i][j], 0, 0, 0);
    }

    #pragma unroll
    for (int j = 0; j < 4; j++) {
        const int col = n0 + wc*64 + j*16 + lx;
        const float bval = bias[col] * bscale;
        const int hh = col >> 6, d = col & 63;
        #pragma unroll
        for (int i = 0; i < 4; i++) {
            const int rbase = m0 + wr*64 + i*16 + lg*4;
            const int bb = rbase >> 11, s = rbase & 2047;
            const float v0 = acc[i][j][0] + bval;
            const float v1 = acc[i][j][1] + bval;
            const float v2 = acc[i][j][2] + bval;
            const float v3 = acc[i][j][3] + bval;
            if (mode == 1) {
                of32[(size_t)(rbase+0)*HID + col] = v0;
                of32[(size_t)(rbase+1)*HID + col] = v1;
                of32[(size_t)(rbase+2)*HID + col] = v2;
                of32[(size_t)(rbase+3)*HID + col] = v3;
            } else if (z == 2) {
                uint2 ow; ow.x = pk2bf(v0, v1); ow.y = pk2bf(v2, v3);
                *(uint2*)&ovt[(((size_t)bb*NH + hh)*HD + d)*S_LEN + s] = ow;
            } else {
                u16* base = obf + (size_t)z * ((size_t)2*S_LEN*HID);
                base[(((size_t)bb*NH + hh)*S_LEN + s+0)*HD + d] = f2bf(v0);
                base[(((size_t)bb*NH + hh)*S_LEN + s+1)*HD + d] = f2bf(v1);
                base[(((size_t)bb*NH + hh)*S_LEN + s+2)*HD + d] = f2bf(v2);
                base[(((size_t)bb*NH + hh)*S_LEN + s+3)*HD + d] = f2bf(v3);
            }
        }
    }
}

// ---------------------------------------------------------------------------
// Flash attention, split-K x2, 32x32x16 MFMA, frag-major K/V LDS, static max.
// Round 13: SINGLE-buffer K/V (32KB LDS total) -> 5 blocks/CU
// (__launch_bounds__(256,5)); round-8-proven 2-barrier loop; T14 early stage.
// ---------------------------------------------------------------------------
__global__ __launch_bounds__(256, 5) void attn_split(
    const u16* __restrict__ Q, const u16* __restrict__ K,
    const u16* __restrict__ Vt, const float* __restrict__ fAg,
    const float* __restrict__ fBg, const int* __restrict__ gmask,
    u16* __restrict__ O0, u16* __restrict__ O1, float* __restrict__ Lp)
{
    __shared__ __align__(16) u16 Ks[8*64*8];   // 8KB
    __shared__ __align__(16) u16 Vs[8*64*8];   // 8KB
    __shared__ __align__(16) u16 Ps[4*2048];   // 16KB (per-wave 4KB)

    const int tid = threadIdx.x;
    const int w   = tid >> 6;
    const int l   = tid & 63;
    const int hi  = l >> 5;
    const int ln31 = l & 31;

    // XCD swizzle: 768 = 8 * 96 (bijective)
    const int bid = blockIdx.x;
    const int swz = (bid & 7) * 96 + (bid >> 3);
    const int half = swz & 1;
    const int q0  = ((swz >> 1) & 15) * 128;
    const int hb  = swz >> 5;
    const int h   = hb % NH;
    const int b   = hb / NH;
    const size_t bh = ((size_t)b*NH + h) * S_LEN;

    const int q_glob = q0 + 32*w + ln31;

    short8v aq[4];
    {
        const u16* qp = Q + (bh + q_glob)*HD + 8*hi;
        aq[0] = *(const short8v*)(qp);
        aq[1] = *(const short8v*)(qp + 16);
        aq[2] = *(const short8v*)(qp + 32);
        aq[3] = *(const short8v*)(qp + 48);
    }
    const int gq = gmask[(size_t)b*S_LEN + q_glob];
    const float* fAb_ = fAg + (size_t)b*S_LEN;
    const float* fBb_ = fBg + (size_t)b*S_LEN;
    const float* fPb_ = gq ? fAb_ : fBb_;

    float l_i = 0.f;
    f32x16 oa0, oa1;
    #pragma unroll
    for (int i = 0; i < 16; i++) { oa0[i] = 0.f; oa1[i] = 0.f; }

    const int str = tid >> 2;
    const int stc = tid & 3;
    const int wbase = ((str >> 5)*4 + stc)*512 + (str & 31)*8;
    const u16* Kbase = K + bh * HD;
    const u16* Vbase = Vt + (size_t)(b*NH + h) * HD * S_LEN;
    char* Pb = (char*)(Ps + w*2048);

    uint4 rk0, rk1, rv0, rv1;

#define STAGE_REGS(KT) do {                                                   \
    const int kk0_ = (KT) * 64;                                               \
    const u16* kp_ = Kbase + (size_t)(kk0_ + str)*HD + stc*16;                \
    rk0 = *(const uint4*)(kp_); rk1 = *(const uint4*)(kp_ + 8);               \
    const u16* vp_ = Vbase + (size_t)str*S_LEN + kk0_ + stc*16;               \
    rv0 = *(const uint4*)(vp_); rv1 = *(const uint4*)(vp_ + 8);               \
} while(0)

#define WRITE_LDS() do {                                                      \
    *(uint4*)(Ks + wbase)       = rk0;                                        \
    *(uint4*)(Ks + wbase + 256) = rk1;                                        \
    *(uint4*)(Vs + wbase)       = rv0;                                        \
    *(uint4*)(Vs + wbase + 256) = rv1;                                        \
} while(0)

#define COMPUTE(K0) do {                                                      \
    f32x16 s0, s1;                                                            \
    const int diff_ = (K0) - q0;                                              \
    if (diff_ == 0 || diff_ == 64) {                                          \
        cinit_uni(s0, fAb_ + (K0) + 4*hi);                                    \
        cinit_uni(s1, fAb_ + (K0) + 32 + 4*hi);                               \
    } else if (diff_ >= 256 || diff_ <= -192) {                               \
        cinit_uni(s0, fPb_ + (K0) + 4*hi);                                    \
        cinit_uni(s1, fPb_ + (K0) + 32 + 4*hi);                               \
    } else {                                                                  \
        cinit_mixed(s0, fAb_ + (K0) + 4*hi, fBb_ + (K0) + 4*hi,               \
                    q_glob - ((K0) + 4*hi), gq);                              \
        cinit_mixed(s1, fAb_ + (K0) + 32 + 4*hi, fBb_ + (K0) + 32 + 4*hi,     \
                    q_glob - ((K0) + 32 + 4*hi), gq);                         \
    }                                                                         \
    __builtin_amdgcn_s_setprio(1);                                            \
    _Pragma("unroll")                                                         \
    for (int dd = 0; dd < 4; dd++) {                                          \
        short8v ak0 = *(const short8v*)(Ks + dd*512 + l*8);                   \
        short8v ak1 = *(const short8v*)(Ks + (4+dd)*512 + l*8);               \
        s0 = __builtin_amdgcn_mfma_f32_32x32x16_bf16(ak0, aq[dd], s0, 0,0,0); \
        s1 = __builtin_amdgcn_mfma_f32_32x32x16_bf16(ak1, aq[dd], s1, 0,0,0); \
    }                                                                         \
    __builtin_amdgcn_s_setprio(0);                                            \
    _Pragma("unroll")                                                         \
    for (int i = 0; i < 16; i++) {                                            \
        s0[i] = exp2_fast(s0[i]);                                             \
        s1[i] = exp2_fast(s1[i]);                                             \
    }                                                                         \
    {                                                                         \
        float a0 = (s0[0]+s0[1]) + (s0[2]+s0[3]);                             \
        float a1 = (s0[4]+s0[5]) + (s0[6]+s0[7]);                             \
        float a2 = (s0[8]+s0[9]) + (s0[10]+s0[11]);                           \
        float a3 = (s0[12]+s0[13]) + (s0[14]+s0[15]);                         \
        float b0 = (s1[0]+s1[1]) + (s1[2]+s1[3]);                             \
        float b1 = (s1[4]+s1[5]) + (s1[6]+s1[7]);                             \
        float b2 = (s1[8]+s1[9]) + (s1[10]+s1[11]);                           \
        float b3 = (s1[12]+s1[13]) + (s1[14]+s1[15]);                         \
        l_i += ((a0+a1)+(a2+a3)) + ((b0+b1)+(b2+b3));                         \
    }                                                                         \
    _Pragma("unroll")                                                         \
    for (int g = 0; g < 4; g++) {                                             \
        uint2 v0, v1;                                                         \
        v0.x = pk2bf(s0[4*g+0], s0[4*g+1]);                                   \
        v0.y = pk2bf(s0[4*g+2], s0[4*g+3]);                                   \
        v1.x = pk2bf(s1[4*g+0], s1[4*g+1]);                                   \
        v1.y = pk2bf(s1[4*g+2], s1[4*g+3]);                                   \
        const int g0_ = g, g1_ = g + 4;                                       \
        *(uint2*)(Pb + (g0_>>1)*1024 + (((g0_&1)<<5) | ln31)*16 + hi*8) = v0; \
        *(uint2*)(Pb + (g1_>>1)*1024 + (((g1_&1)<<5) | ln31)*16 + hi*8) = v1; \
    }                                                                         \
    __builtin_amdgcn_s_setprio(1);                                            \
    _Pragma("unroll")                                                         \
    for (int c = 0; c < 4; c++) {                                             \
        short8v pb  = *(const short8v*)(Pb + c*1024 + l*16);                  \
        short8v av0 = *(const short8v*)(Vs + c*512 + l*8);                    \
        short8v av1 = *(const short8v*)(Vs + (4+c)*512 + l*8);                \
        oa0 = __builtin_amdgcn_mfma_f32_32x32x16_bf16(av0, pb, oa0, 0,0,0);   \
        oa1 = __builtin_amdgcn_mfma_f32_32x32x16_bf16(av1, pb, oa1, 0,0,0);   \
    }                                                                         \
    __builtin_amdgcn_s_setprio(0);                                            \
} while(0)

    const int t0 = half * 16, t1 = t0 + 16;
    STAGE_REGS(t0);
    WRITE_LDS();
    __syncthreads();

    for (int kt = t0; kt < t1; kt++) {
        const int kn = (kt+1 < t1) ? (kt+1) : kt;
        STAGE_REGS(kn);               // issue next tile loads early (T14)
        COMPUTE(kt*64);
        __syncthreads();              // reads of single buffer done
        WRITE_LDS();
        __syncthreads();              // writes visible
    }

#undef STAGE_REGS
#undef WRITE_LDS
#undef COMPUTE

    // epilogue: combine l across hi-halves once; write unnormalized O + l.
    l_i += __shfl_xor(l_i, 32);
    {
        u16* op = (half ? O1 : O0) + (bh + q_glob)*HD + 4*hi;
        #pragma unroll
        for (int m = 0; m < 4; m++) {
            *(unsigned*)(op + 8*m)          = pk2bf(oa0[4*m],   oa0[4*m+1]);
            *(unsigned*)(op + 8*m + 2)      = pk2bf(oa0[4*m+2], oa0[4*m+3]);
            *(unsigned*)(op + 32 + 8*m)     = pk2bf(oa1[4*m],   oa1[4*m+1]);
            *(unsigned*)(op + 32 + 8*m + 2) = pk2bf(oa1[4*m+2], oa1[4*m+3]);
        }
        if (l < 32) Lp[half*NROW + bh + q_glob] = l_i;
    }
}

// ---------------------------------------------------------------------------
extern "C" void kernel_launch(void* const* d_in, const int* in_sizes, int n_in,
                              void* d_out, int out_size, void* d_ws, size_t ws_size,
                              hipStream_t stream)
{
    const float* hidden = (const float*)d_in[0];
    const int*   amask  = (const int*)d_in[1];
    const int*   gmask  = (const int*)d_in[2];
    const float* Wq = (const float*)d_in[3];
    const float* bq = (const float*)d_in[4];
    const float* Wk = (const float*)d_in[5];
    const float* bk = (const float*)d_in[6];
    const float* Wv = (const float*)d_in[7];
    const float* bv = (const float*)d_in[8];
    const float* Wo = (const float*)d_in[9];
    const float* bo = (const float*)d_in[10];
    float* out = (float*)d_out;

    char* ws = (char*)d_ws;
    const size_t NTOK = (size_t)2 * S_LEN * HID;   // 3,145,728
    u16* hbf   = (u16*)(ws);                       // hidden bf16; later O1 partial
    u16* w4    = (u16*)(ws + 6291456);             // Wq',Wk,Wv,Wo bf16
    float* Lp  = (float*)(ws + 6291456);           // overlays Wq slice post-QKV
    u16* qkvbf = (u16*)(ws + 11010048);            // Q, K (2 x NTOK)
    float* fAg = (float*)(ws + 23592960);          // mask addends
    float* fBg = (float*)(ws + 23609344);
    u16* vtbf  = (u16*)(ws + 29884416);            // Vt
    u16* aobf  = (u16*)(ws + 36175872);            // O0 partial

    convert_inputs<<<dim3(1536, 6), 256, 0, stream>>>(
        hidden, Wq, Wk, Wv, Wo, amask, gmask, hbf, w4, fAg, fBg);

    gemm_mfma<<<dim3(32, 6, 3), 256, 0, stream>>>(
        hbf, w4, bq, bk, bv, qkvbf, vtbf, nullptr, nullptr, nullptr, nullptr, 0);

    u16* Qbf = qkvbf;
    u16* Kbf = qkvbf + NTOK;

    attn_split<<<dim3(768), 256, 0, stream>>>(Qbf, Kbf, vtbf, fAg, fBg, gmask,
                                              aobf, hbf, Lp);

    // final projection with fused split-K merge (attn_merge kernel deleted)
    gemm_mfma<<<dim3(32, 6), 256, 0, stream>>>(
        nullptr, w4, bo, nullptr, nullptr, nullptr, nullptr, out,
        aobf, hbf, Lp, 1);
}

// Round 14
// 121.720 us; speedup vs baseline: 1.3357x; 1.3357x over previous
//
#include <hip/hip_runtime.h>
#include <math.h>

#define S_LEN 2048
#define HID   768
#define NH    12
#define HD    64
#define WIN   128
#define NEGV  (-1e30f)
#define QSCALE 0.1803368801111204f   /* 0.125 * log2(e): scores in log2 domain */
#define MCONST 12.0f                 /* static softmax max (log2 domain) */
#define NROW  49152                  /* B*NH*S = 2*12*2048 */

typedef __attribute__((ext_vector_type(8))) short short8v;
typedef __attribute__((ext_vector_type(16))) float f32x16;
typedef unsigned short u16;

__device__ __forceinline__ u16 f2bf(float f) {
    union { float f; unsigned int u; } c; c.f = f;
    unsigned int u = c.u + 0x7FFFu + ((c.u >> 16) & 1u);
    return (u16)(u >> 16);
}

__device__ __forceinline__ short8v cvt8(float4 a, float4 b) {
    short8v t;
    t[0]=(short)f2bf(a.x); t[1]=(short)f2bf(a.y); t[2]=(short)f2bf(a.z); t[3]=(short)f2bf(a.w);
    t[4]=(short)f2bf(b.x); t[5]=(short)f2bf(b.y); t[6]=(short)f2bf(b.z); t[7]=(short)f2bf(b.w);
    return t;
}

__device__ __forceinline__ unsigned int pk2bf(float a, float b) {
    unsigned int r;
    asm("v_cvt_pk_bf16_f32 %0, %1, %2" : "=v"(r) : "v"(a), "v"(b));
    return r;
}

__device__ __forceinline__ float exp2_fast(float x) {
    float r;
    asm("v_exp_f32 %0, %1" : "=v"(r) : "v"(x));
    return r;
}

__device__ __forceinline__ float bf2f(u16 v) {
    union { float f; unsigned u; } c; c.u = ((unsigned)v) << 16; return c.f;
}

__device__ __forceinline__ void gload_lds16(const void* g, void* l) {
    __builtin_amdgcn_global_load_lds(
        (const __attribute__((address_space(1))) unsigned int*)g,
        (__attribute__((address_space(3))) unsigned int*)l, 16, 0, 0);
}

// C-init builders: S[4m+c] = src[8m + c]
__device__ __forceinline__ void cinit_uni(f32x16& S, const float* src) {
    #pragma unroll
    for (int m = 0; m < 4; m++) {
        float4 f = *(const float4*)(src + 8*m);
        S[4*m+0]=f.x; S[4*m+1]=f.y; S[4*m+2]=f.z; S[4*m+3]=f.w;
    }
}
__device__ __forceinline__ void cinit_mixed(f32x16& S, const float* fa, const float* fb,
                                            int ebase, int gq) {
    #pragma unroll
    for (int m = 0; m < 4; m++) {
        float4 a = *(const float4*)(fa + 8*m);
        float4 b = *(const float4*)(fb + 8*m);
        const int e = ebase - 8*m;
        S[4*m+0] = (gq || (unsigned)(e     + 128) <= 256u) ? a.x : b.x;
        S[4*m+1] = (gq || (unsigned)(e - 1 + 128) <= 256u) ? a.y : b.y;
        S[4*m+2] = (gq || (unsigned)(e - 2 + 128) <= 256u) ? a.z : b.z;
        S[4*m+3] = (gq || (unsigned)(e - 3 + 128) <= 256u) ? a.w : b.w;
    }
}

// ---------------------------------------------------------------------------
// Convert hidden + 4 weights to bf16; y=5: mask addends (with -MCONST folded).
// ---------------------------------------------------------------------------
__global__ __launch_bounds__(256) void convert_inputs(
    const float* __restrict__ hidden, const float* __restrict__ Wq,
    const float* __restrict__ Wk, const float* __restrict__ Wv,
    const float* __restrict__ Wo, const int* __restrict__ amask,
    const int* __restrict__ gmask, u16* __restrict__ hbf,
    u16* __restrict__ w4, float* __restrict__ fAg, float* __restrict__ fBg)
{
    const int y = blockIdx.y;
    if (y == 5) {
        const int idx = (blockIdx.x*256 + threadIdx.x) * 8;
        if (idx >= 2*S_LEN) return;
        #pragma unroll
        for (int u = 0; u < 8; u++) {
            const int am = amask[idx+u], gk = gmask[idx+u];
            fAg[idx+u] = am ? -MCONST : NEGV;
            fBg[idx+u] = (am && gk) ? -MCONST : NEGV;
        }
        return;
    }
    const float* src; u16* dst; int n; float scale = 1.f;
    if (y == 0) { src = hidden; dst = hbf; n = 4096*HID; }
    else {
        src = (y==1) ? Wq : (y==2) ? Wk : (y==3) ? Wv : Wo;
        dst = w4 + (size_t)(y-1)*HID*HID;
        n = HID*HID;
        if (y == 1) scale = QSCALE;
    }
    const int idx = (blockIdx.x*256 + threadIdx.x) * 8;
    if (idx >= n) return;
    float4 f0 = *(const float4*)(src + idx);
    float4 f1 = *(const float4*)(src + idx + 4);
    f0.x*=scale; f0.y*=scale; f0.z*=scale; f0.w*=scale;
    f1.x*=scale; f1.y*=scale; f1.z*=scale; f1.w*=scale;
    *(short8v*)(dst + idx) = cvt8(f0, f1);
}

// ---------------------------------------------------------------------------
// bf16 MFMA GEMM (m97 structure).
// mode 0: z in {0,1,2}: Q,K -> obf + z*NTOK; V (z=2) -> ovt transposed.
// mode 1: Wo; A-operand FUSED-MERGED from split-K partials O0m/O1m/Lpm;
//         out f32 flat (B,S,H).
// ---------------------------------------------------------------------------
typedef __attribute__((ext_vector_type(4))) float float4v;
__global__ __launch_bounds__(256) void gemm_mfma(
    const u16* __restrict__ A, const u16* __restrict__ W4,
    const float* __restrict__ bA, const float* __restrict__ bB,
    const float* __restrict__ bC, u16* __restrict__ obf,
    u16* __restrict__ ovt, float* __restrict__ of32,
    const u16* __restrict__ O0m, const u16* __restrict__ O1m,
    const float* __restrict__ Lpm, int mode)
{
    __shared__ __align__(16) u16 As[128*32];
    __shared__ __align__(16) u16 Bs[128*32];

    const int tid = threadIdx.x;
    const int w = tid >> 6, l = tid & 63;
    const int lx = l & 15, lg = l >> 4;
    const int wr = w >> 1, wc = w & 1;
    const int m0 = blockIdx.x * 128, n0 = blockIdx.y * 128;
    const int z = (mode == 0) ? blockIdx.z : 3;
    const float* bias = (mode == 1) ? bA : (z == 0 ? bA : (z == 1 ? bB : bC));
    const float bscale = (mode == 0 && z == 0) ? QSCALE : 1.0f;
    const u16* Wp = W4 + (size_t)z * (HID*HID);

    float4v acc[4][4];
    const float4v fz = {0.f,0.f,0.f,0.f};
    #pragma unroll
    for (int i = 0; i < 4; i++)
        #pragma unroll
        for (int j = 0; j < 4; j++) acc[i][j] = fz;

    for (int kt = 0; kt < HID/32; kt++) {
        const int k0 = kt * 32;
        __syncthreads();
        #pragma unroll
        for (int rnd = 0; rnd < 2; rnd++) {
            const int ch  = rnd*256 + w*64 + l;
            const int row = ch >> 2, kc = ch & 3;
            if (mode == 1) {
                // fused split-K merge: A[m][kk] = (O0+O1)/(l0+l1), bf16
                const int m  = m0 + row;
                const int kk = k0 + kc*8;
                const int bb2 = m >> 11, s2 = m & 2047;
                const int hh2 = kk >> 6, d2 = kk & 63;
                const size_t rowO = ((size_t)bb2*NH + hh2)*S_LEN + s2;
                uint4 a0 = *(const uint4*)(O0m + rowO*HD + d2);
                uint4 a1 = *(const uint4*)(O1m + rowO*HD + d2);
                const float inv = 1.f / (Lpm[rowO] + Lpm[rowO + NROW]);
                const u16* p0 = (const u16*)&a0;
                const u16* p1 = (const u16*)&a1;
                short8v mm;
                #pragma unroll
                for (int j2 = 0; j2 < 8; j2++)
                    mm[j2] = (short)f2bf((bf2f(p0[j2]) + bf2f(p1[j2])) * inv);
                *(short8v*)(As + (size_t)ch*8) = mm;
            } else {
                gload_lds16(A + (size_t)(m0+row)*HID + k0 + kc*8,
                            As + (size_t)(rnd*256 + w*64)*8);
            }
            gload_lds16(Wp + (size_t)(n0+row)*HID + k0 + kc*8,
                        Bs + (size_t)(rnd*256 + w*64)*8);
        }
        __syncthreads();
        short8v af[4], bfr[4];
        #pragma unroll
        for (int i = 0; i < 4; i++) {
            af[i]  = *(const short8v*)(As + (wr*64 + i*16 + lx)*32 + lg*8);
            bfr[i] = *(const short8v*)(Bs + (wc*64 + i*16 + lx)*32 + lg*8);
        }
        #pragma unroll
        for (int i = 0; i < 4; i++)
            #pragma unroll
            for (int j = 0; j < 4; j++)
                acc[i][j] = __builtin_amdgcn_mfma_f32_16x16x32_bf16(af[i], bfr[j], acc[i][j], 0, 0, 0);
    }

    #pragma unroll
    for (int j = 0; j < 4; j++) {
        const int col = n0 + wc*64 + j*16 + lx;
        const float bval = bias[col] * bscale;
        const int hh = col >> 6, d = col & 63;
        #pragma unroll
        for (int i = 0; i < 4; i++) {
            const int rbase = m0 + wr*64 + i*16 + lg*4;
            const int bb = rbase >> 11, s = rbase & 2047;
            const float v0 = acc[i][j][0] + bval;
            const float v1 = acc[i][j][1] + bval;
            const float v2 = acc[i][j][2] + bval;
            const float v3 = acc[i][j][3] + bval;
            if (mode == 1) {
                of32[(size_t)(rbase+0)*HID + col] = v0;
                of32[(size_t)(rbase+1)*HID + col] = v1;
                of32[(size_t)(rbase+2)*HID + col] = v2;
                of32[(size_t)(rbase+3)*HID + col] = v3;
            } else if (z == 2) {
                uint2 ow; ow.x = pk2bf(v0, v1); ow.y = pk2bf(v2, v3);
                *(uint2*)&ovt[(((size_t)bb*NH + hh)*HD + d)*S_LEN + s] = ow;
            } else {
                u16* base = obf + (size_t)z * ((size_t)2*S_LEN*HID);
                base[(((size_t)bb*NH + hh)*S_LEN + s+0)*HD + d] = f2bf(v0);
                base[(((size_t)bb*NH + hh)*S_LEN + s+1)*HD + d] = f2bf(v1);
                base[(((size_t)bb*NH + hh)*S_LEN + s+2)*HD + d] = f2bf(v2);
                base[(((size_t)bb*NH + hh)*S_LEN + s+3)*HD + d] = f2bf(v3);
            }
        }
    }
}

// ---------------------------------------------------------------------------
// Flash attention, split-K x2, 32x32x16 MFMA, frag-major K/V LDS, static max.
// Round 14: __launch_bounds__(256,4) — VGPR cap 128 >= natural 84, NO spills
// (round 13's (256,5) forced VGPR 48 -> 74MB scratch traffic, 2x regression).
// LDS 32KB/block still allows 5 blocks/CU; VGPR 84 allows 5 waves/SIMD.
// ---------------------------------------------------------------------------
__global__ __launch_bounds__(256, 4) void attn_split(
    const u16* __restrict__ Q, const u16* __restrict__ K,
    const u16* __restrict__ Vt, const float* __restrict__ fAg,
    const float* __restrict__ fBg, const int* __restrict__ gmask,
    u16* __restrict__ O0, u16* __restrict__ O1, float* __restrict__ Lp)
{
    __shared__ __align__(16) u16 Ks[8*64*8];   // 8KB
    __shared__ __align__(16) u16 Vs[8*64*8];   // 8KB
    __shared__ __align__(16) u16 Ps[4*2048];   // 16KB (per-wave 4KB)

    const int tid = threadIdx.x;
    const int w   = tid >> 6;
    const int l   = tid & 63;
    const int hi  = l >> 5;
    const int ln31 = l & 31;

    // XCD swizzle: 768 = 8 * 96 (bijective)
    const int bid = blockIdx.x;
    const int swz = (bid & 7) * 96 + (bid >> 3);
    const int half = swz & 1;
    const int q0  = ((swz >> 1) & 15) * 128;
    const int hb  = swz >> 5;
    const int h   = hb % NH;
    const int b   = hb / NH;
    const size_t bh = ((size_t)b*NH + h) * S_LEN;

    const int q_glob = q0 + 32*w + ln31;

    short8v aq[4];
    {
        const u16* qp = Q + (bh + q_glob)*HD + 8*hi;
        aq[0] = *(const short8v*)(qp);
        aq[1] = *(const short8v*)(qp + 16);
        aq[2] = *(const short8v*)(qp + 32);
        aq[3] = *(const short8v*)(qp + 48);
    }
    const int gq = gmask[(size_t)b*S_LEN + q_glob];
    const float* fAb_ = fAg + (size_t)b*S_LEN;
    const float* fBb_ = fBg + (size_t)b*S_LEN;
    const float* fPb_ = gq ? fAb_ : fBb_;

    float l_i = 0.f;
    f32x16 oa0, oa1;
    #pragma unroll
    for (int i = 0; i < 16; i++) { oa0[i] = 0.f; oa1[i] = 0.f; }

    const int str = tid >> 2;
    const int stc = tid & 3;
    const int wbase = ((str >> 5)*4 + stc)*512 + (str & 31)*8;
    const u16* Kbase = K + bh * HD;
    const u16* Vbase = Vt + (size_t)(b*NH + h) * HD * S_LEN;
    char* Pb = (char*)(Ps + w*2048);

    uint4 rk0, rk1, rv0, rv1;

#define STAGE_REGS(KT) do {                                                   \
    const int kk0_ = (KT) * 64;                                               \
    const u16* kp_ = Kbase + (size_t)(kk0_ + str)*HD + stc*16;                \
    rk0 = *(const uint4*)(kp_); rk1 = *(const uint4*)(kp_ + 8);               \
    const u16* vp_ = Vbase + (size_t)str*S_LEN + kk0_ + stc*16;               \
    rv0 = *(const uint4*)(vp_); rv1 = *(const uint4*)(vp_ + 8);               \
} while(0)

#define WRITE_LDS() do {                                                      \
    *(uint4*)(Ks + wbase)       = rk0;                                        \
    *(uint4*)(Ks + wbase + 256) = rk1;                                        \
    *(uint4*)(Vs + wbase)       = rv0;                                        \
    *(uint4*)(Vs + wbase + 256) = rv1;                                        \
} while(0)

#define COMPUTE(K0) do {                                                      \
    f32x16 s0, s1;                                                            \
    const int diff_ = (K0) - q0;                                              \
    if (diff_ == 0 || diff_ == 64) {                                          \
        cinit_uni(s0, fAb_ + (K0) + 4*hi);                                    \
        cinit_uni(s1, fAb_ + (K0) + 32 + 4*hi);                               \
    } else if (diff_ >= 256 || diff_ <= -192) {                               \
        cinit_uni(s0, fPb_ + (K0) + 4*hi);                                    \
        cinit_uni(s1, fPb_ + (K0) + 32 + 4*hi);                               \
    } else {                                                                  \
        cinit_mixed(s0, fAb_ + (K0) + 4*hi, fBb_ + (K0) + 4*hi,               \
                    q_glob - ((K0) + 4*hi), gq);                              \
        cinit_mixed(s1, fAb_ + (K0) + 32 + 4*hi, fBb_ + (K0) + 32 + 4*hi,     \
                    q_glob - ((K0) + 32 + 4*hi), gq);                         \
    }                                                                         \
    __builtin_amdgcn_s_setprio(1);                                            \
    _Pragma("unroll")                                                         \
    for (int dd = 0; dd < 4; dd++) {                                          \
        short8v ak0 = *(const short8v*)(Ks + dd*512 + l*8);                   \
        short8v ak1 = *(const short8v*)(Ks + (4+dd)*512 + l*8);               \
        s0 = __builtin_amdgcn_mfma_f32_32x32x16_bf16(ak0, aq[dd], s0, 0,0,0); \
        s1 = __builtin_amdgcn_mfma_f32_32x32x16_bf16(ak1, aq[dd], s1, 0,0,0); \
    }                                                                         \
    __builtin_amdgcn_s_setprio(0);                                            \
    _Pragma("unroll")                                                         \
    for (int i = 0; i < 16; i++) {                                            \
        s0[i] = exp2_fast(s0[i]);                                             \
        s1[i] = exp2_fast(s1[i]);                                             \
    }                                                                         \
    {                                                                         \
        float a0 = (s0[0]+s0[1]) + (s0[2]+s0[3]);                             \
        float a1 = (s0[4]+s0[5]) + (s0[6]+s0[7]);                             \
        float a2 = (s0[8]+s0[9]) + (s0[10]+s0[11]);                           \
        float a3 = (s0[12]+s0[13]) + (s0[14]+s0[15]);                         \
        float b0 = (s1[0]+s1[1]) + (s1[2]+s1[3]);                             \
        float b1 = (s1[4]+s1[5]) + (s1[6]+s1[7]);                             \
        float b2 = (s1[8]+s1[9]) + (s1[10]+s1[11]);                           \
        float b3 = (s1[12]+s1[13]) + (s1[14]+s1[15]);                         \
        l_i += ((a0+a1)+(a2+a3)) + ((b0+b1)+(b2+b3));                         \
    }                                                                         \
    _Pragma("unroll")                                                         \
    for (int g = 0; g < 4; g++) {                                             \
        uint2 v0, v1;                                                         \
        v0.x = pk2bf(s0[4*g+0], s0[4*g+1]);                                   \
        v0.y = pk2bf(s0[4*g+2], s0[4*g+3]);                                   \
        v1.x = pk2bf(s1[4*g+0], s1[4*g+1]);                                   \
        v1.y = pk2bf(s1[4*g+2], s1[4*g+3]);                                   \
        const int g0_ = g, g1_ = g + 4;                                       \
        *(uint2*)(Pb + (g0_>>1)*1024 + (((g0_&1)<<5) | ln31)*16 + hi*8) = v0; \
        *(uint2*)(Pb + (g1_>>1)*1024 + (((g1_&1)<<5) | ln31)*16 + hi*8) = v1; \
    }                                                                         \
    __builtin_amdgcn_s_setprio(1);                                            \
    _Pragma("unroll")                                                         \
    for (int c = 0; c < 4; c++) {                                             \
        short8v pb  = *(const short8v*)(Pb + c*1024 + l*16);                  \
        short8v av0 = *(const short8v*)(Vs + c*512 + l*8);                    \
        short8v av1 = *(const short8v*)(Vs + (4+c)*512 + l*8);                \
        oa0 = __builtin_amdgcn_mfma_f32_32x32x16_bf16(av0, pb, oa0, 0,0,0);   \
        oa1 = __builtin_amdgcn_mfma_f32_32x32x16_bf16(av1, pb, oa1, 0,0,0);   \
    }                                                                         \
    __builtin_amdgcn_s_setprio(0);                                            \
} while(0)

    const int t0 = half * 16, t1 = t0 + 16;
    STAGE_REGS(t0);
    WRITE_LDS();
    __syncthreads();

    for (int kt = t0; kt < t1; kt++) {
        const int kn = (kt+1 < t1) ? (kt+1) : kt;
        STAGE_REGS(kn);               // issue next tile loads early (T14)
        COMPUTE(kt*64);
        __syncthreads();              // reads of single buffer done
        WRITE_LDS();
        __syncthreads();              // writes visible
    }

#undef STAGE_REGS
#undef WRITE_LDS
#undef COMPUTE

    // epilogue: combine l across hi-halves once; write unnormalized O + l.
    l_i += __shfl_xor(l_i, 32);
    {
        u16* op = (half ? O1 : O0) + (bh + q_glob)*HD + 4*hi;
        #pragma unroll
        for (int m = 0; m < 4; m++) {
            *(unsigned*)(op + 8*m)          = pk2bf(oa0[4*m],   oa0[4*m+1]);
            *(unsigned*)(op + 8*m + 2)      = pk2bf(oa0[4*m+2], oa0[4*m+3]);
            *(unsigned*)(op + 32 + 8*m)     = pk2bf(oa1[4*m],   oa1[4*m+1]);
            *(unsigned*)(op + 32 + 8*m + 2) = pk2bf(oa1[4*m+2], oa1[4*m+3]);
        }
        if (l < 32) Lp[half*NROW + bh + q_glob] = l_i;
    }
}

// ---------------------------------------------------------------------------
extern "C" void kernel_launch(void* const* d_in, const int* in_sizes, int n_in,
                              void* d_out, int out_size, void* d_ws, size_t ws_size,
                              hipStream_t stream)
{
    const float* hidden = (const float*)d_in[0];
    const int*   amask  = (const int*)d_in[1];
    const int*   gmask  = (const int*)d_in[2];
    const float* Wq = (const float*)d_in[3];
    const float* bq = (const float*)d_in[4];
    const float* Wk = (const float*)d_in[5];
    const float* bk = (const float*)d_in[6];
    const float* Wv = (const float*)d_in[7];
    const float* bv = (const float*)d_in[8];
    const float* Wo = (const float*)d_in[9];
    const float* bo = (const float*)d_in[10];
    float* out = (float*)d_out;

    char* ws = (char*)d_ws;
    const size_t NTOK = (size_t)2 * S_LEN * HID;   // 3,145,728
    u16* hbf   = (u16*)(ws);                       // hidden bf16; later O1 partial
    u16* w4    = (u16*)(ws + 6291456);             // Wq',Wk,Wv,Wo bf16
    float* Lp  = (float*)(ws + 6291456);           // overlays Wq slice post-QKV
    u16* qkvbf = (u16*)(ws + 11010048);            // Q, K (2 x NTOK)
    float* fAg = (float*)(ws + 23592960);          // mask addends
    float* fBg = (float*)(ws + 23609344);
    u16* vtbf  = (u16*)(ws + 29884416);            // Vt
    u16* aobf  = (u16*)(ws + 36175872);            // O0 partial

    convert_inputs<<<dim3(1536, 6), 256, 0, stream>>>(
        hidden, Wq, Wk, Wv, Wo, amask, gmask, hbf, w4, fAg, fBg);

    gemm_mfma<<<dim3(32, 6, 3), 256, 0, stream>>>(
        hbf, w4, bq, bk, bv, qkvbf, vtbf, nullptr, nullptr, nullptr, nullptr, 0);

    u16* Qbf = qkvbf;
    u16* Kbf = qkvbf + NTOK;

    attn_split<<<dim3(768), 256, 0, stream>>>(Qbf, Kbf, vtbf, fAg, fBg, gmask,
                                              aobf, hbf, Lp);

    // final projection with fused split-K merge (attn_merge kernel deleted)
    gemm_mfma<<<dim3(32, 6), 256, 0, stream>>>(
        nullptr, w4, bo, nullptr, nullptr, nullptr, nullptr, out,
        aobf, hbf, Lp, 1);
}

// Round 15
// 106.296 us; speedup vs baseline: 1.5295x; 1.1451x over previous
//
#include <hip/hip_runtime.h>
#include <math.h>

#define S_LEN 2048
#define HID   768
#define NH    12
#define HD    64
#define WIN   128
#define NEGV  (-1e30f)
#define QSCALE 0.1803368801111204f   /* 0.125 * log2(e): scores in log2 domain */
#define MCONST 12.0f                 /* static softmax max (log2 domain) */
#define NROW  49152                  /* B*NH*S = 2*12*2048 */

typedef __attribute__((ext_vector_type(8))) short short8v;
typedef __attribute__((ext_vector_type(16))) float f32x16;
typedef unsigned short u16;

__device__ __forceinline__ u16 f2bf(float f) {
    union { float f; unsigned int u; } c; c.f = f;
    unsigned int u = c.u + 0x7FFFu + ((c.u >> 16) & 1u);
    return (u16)(u >> 16);
}

__device__ __forceinline__ short8v cvt8(float4 a, float4 b) {
    short8v t;
    t[0]=(short)f2bf(a.x); t[1]=(short)f2bf(a.y); t[2]=(short)f2bf(a.z); t[3]=(short)f2bf(a.w);
    t[4]=(short)f2bf(b.x); t[5]=(short)f2bf(b.y); t[6]=(short)f2bf(b.z); t[7]=(short)f2bf(b.w);
    return t;
}

__device__ __forceinline__ unsigned int pk2bf(float a, float b) {
    unsigned int r;
    asm("v_cvt_pk_bf16_f32 %0, %1, %2" : "=v"(r) : "v"(a), "v"(b));
    return r;
}

__device__ __forceinline__ float exp2_fast(float x) {
    float r;
    asm("v_exp_f32 %0, %1" : "=v"(r) : "v"(x));
    return r;
}

__device__ __forceinline__ float bf2f(u16 v) {
    union { float f; unsigned u; } c; c.u = ((unsigned)v) << 16; return c.f;
}

__device__ __forceinline__ void gload_lds16(const void* g, void* l) {
    __builtin_amdgcn_global_load_lds(
        (const __attribute__((address_space(1))) unsigned int*)g,
        (__attribute__((address_space(3))) unsigned int*)l, 16, 0, 0);
}

// C-init builders: S[4m+c] = src[8m + c]
__device__ __forceinline__ void cinit_uni(f32x16& S, const float* src) {
    #pragma unroll
    for (int m = 0; m < 4; m++) {
        float4 f = *(const float4*)(src + 8*m);
        S[4*m+0]=f.x; S[4*m+1]=f.y; S[4*m+2]=f.z; S[4*m+3]=f.w;
    }
}
__device__ __forceinline__ void cinit_mixed(f32x16& S, const float* fa, const float* fb,
                                            int ebase, int gq) {
    #pragma unroll
    for (int m = 0; m < 4; m++) {
        float4 a = *(const float4*)(fa + 8*m);
        float4 b = *(const float4*)(fb + 8*m);
        const int e = ebase - 8*m;
        S[4*m+0] = (gq || (unsigned)(e     + 128) <= 256u) ? a.x : b.x;
        S[4*m+1] = (gq || (unsigned)(e - 1 + 128) <= 256u) ? a.y : b.y;
        S[4*m+2] = (gq || (unsigned)(e - 2 + 128) <= 256u) ? a.z : b.z;
        S[4*m+3] = (gq || (unsigned)(e - 3 + 128) <= 256u) ? a.w : b.w;
    }
}

// ---------------------------------------------------------------------------
// Convert hidden + 4 weights to bf16; y=5: mask addends (with -MCONST folded).
// ---------------------------------------------------------------------------
__global__ __launch_bounds__(256) void convert_inputs(
    const float* __restrict__ hidden, const float* __restrict__ Wq,
    const float* __restrict__ Wk, const float* __restrict__ Wv,
    const float* __restrict__ Wo, const int* __restrict__ amask,
    const int* __restrict__ gmask, u16* __restrict__ hbf,
    u16* __restrict__ w4, float* __restrict__ fAg, float* __restrict__ fBg)
{
    const int y = blockIdx.y;
    if (y == 5) {
        const int idx = (blockIdx.x*256 + threadIdx.x) * 8;
        if (idx >= 2*S_LEN) return;
        #pragma unroll
        for (int u = 0; u < 8; u++) {
            const int am = amask[idx+u], gk = gmask[idx+u];
            fAg[idx+u] = am ? -MCONST : NEGV;
            fBg[idx+u] = (am && gk) ? -MCONST : NEGV;
        }
        return;
    }
    const float* src; u16* dst; int n; float scale = 1.f;
    if (y == 0) { src = hidden; dst = hbf; n = 4096*HID; }
    else {
        src = (y==1) ? Wq : (y==2) ? Wk : (y==3) ? Wv : Wo;
        dst = w4 + (size_t)(y-1)*HID*HID;
        n = HID*HID;
        if (y == 1) scale = QSCALE;
    }
    const int idx = (blockIdx.x*256 + threadIdx.x) * 8;
    if (idx >= n) return;
    float4 f0 = *(const float4*)(src + idx);
    float4 f1 = *(const float4*)(src + idx + 4);
    f0.x*=scale; f0.y*=scale; f0.z*=scale; f0.w*=scale;
    f1.x*=scale; f1.y*=scale; f1.z*=scale; f1.w*=scale;
    *(short8v*)(dst + idx) = cvt8(f0, f1);
}

// ---------------------------------------------------------------------------
// bf16 MFMA GEMM (m97 structure) — round-12 version (plain A staging).
// mode 0: z in {0,1,2}: Q,K -> obf + z*NTOK; V (z=2) -> ovt transposed.
// mode 1: Wo; out f32 flat (B,S,H).
// ---------------------------------------------------------------------------
typedef __attribute__((ext_vector_type(4))) float float4v;
__global__ __launch_bounds__(256) void gemm_mfma(
    const u16* __restrict__ A, const u16* __restrict__ W4,
    const float* __restrict__ bA, const float* __restrict__ bB,
    const float* __restrict__ bC, u16* __restrict__ obf,
    u16* __restrict__ ovt, float* __restrict__ of32, int mode)
{
    __shared__ __align__(16) u16 As[128*32];
    __shared__ __align__(16) u16 Bs[128*32];

    const int tid = threadIdx.x;
    const int w = tid >> 6, l = tid & 63;
    const int lx = l & 15, lg = l >> 4;
    const int wr = w >> 1, wc = w & 1;
    const int m0 = blockIdx.x * 128, n0 = blockIdx.y * 128;
    const int z = (mode == 0) ? blockIdx.z : 3;
    const float* bias = (mode == 1) ? bA : (z == 0 ? bA : (z == 1 ? bB : bC));
    const float bscale = (mode == 0 && z == 0) ? QSCALE : 1.0f;
    const u16* Wp = W4 + (size_t)z * (HID*HID);

    float4v acc[4][4];
    const float4v fz = {0.f,0.f,0.f,0.f};
    #pragma unroll
    for (int i = 0; i < 4; i++)
        #pragma unroll
        for (int j = 0; j < 4; j++) acc[i][j] = fz;

    for (int kt = 0; kt < HID/32; kt++) {
        const int k0 = kt * 32;
        __syncthreads();
        #pragma unroll
        for (int rnd = 0; rnd < 2; rnd++) {
            const int ch  = rnd*256 + w*64 + l;
            const int row = ch >> 2, kc = ch & 3;
            gload_lds16(A  + (size_t)(m0+row)*HID + k0 + kc*8,
                        As + (size_t)(rnd*256 + w*64)*8);
            gload_lds16(Wp + (size_t)(n0+row)*HID + k0 + kc*8,
                        Bs + (size_t)(rnd*256 + w*64)*8);
        }
        __syncthreads();
        short8v af[4], bfr[4];
        #pragma unroll
        for (int i = 0; i < 4; i++) {
            af[i]  = *(const short8v*)(As + (wr*64 + i*16 + lx)*32 + lg*8);
            bfr[i] = *(const short8v*)(Bs + (wc*64 + i*16 + lx)*32 + lg*8);
        }
        #pragma unroll
        for (int i = 0; i < 4; i++)
            #pragma unroll
            for (int j = 0; j < 4; j++)
                acc[i][j] = __builtin_amdgcn_mfma_f32_16x16x32_bf16(af[i], bfr[j], acc[i][j], 0, 0, 0);
    }

    #pragma unroll
    for (int j = 0; j < 4; j++) {
        const int col = n0 + wc*64 + j*16 + lx;
        const float bval = bias[col] * bscale;
        const int hh = col >> 6, d = col & 63;
        #pragma unroll
        for (int i = 0; i < 4; i++) {
            const int rbase = m0 + wr*64 + i*16 + lg*4;
            const int bb = rbase >> 11, s = rbase & 2047;
            const float v0 = acc[i][j][0] + bval;
            const float v1 = acc[i][j][1] + bval;
            const float v2 = acc[i][j][2] + bval;
            const float v3 = acc[i][j][3] + bval;
            if (mode == 1) {
                of32[(size_t)(rbase+0)*HID + col] = v0;
                of32[(size_t)(rbase+1)*HID + col] = v1;
                of32[(size_t)(rbase+2)*HID + col] = v2;
                of32[(size_t)(rbase+3)*HID + col] = v3;
            } else if (z == 2) {
                uint2 ow; ow.x = pk2bf(v0, v1); ow.y = pk2bf(v2, v3);
                *(uint2*)&ovt[(((size_t)bb*NH + hh)*HD + d)*S_LEN + s] = ow;
            } else {
                u16* base = obf + (size_t)z * ((size_t)2*S_LEN*HID);
                base[(((size_t)bb*NH + hh)*S_LEN + s+0)*HD + d] = f2bf(v0);
                base[(((size_t)bb*NH + hh)*S_LEN + s+1)*HD + d] = f2bf(v1);
                base[(((size_t)bb*NH + hh)*S_LEN + s+2)*HD + d] = f2bf(v2);
                base[(((size_t)bb*NH + hh)*S_LEN + s+3)*HD + d] = f2bf(v3);
            }
        }
    }
}

// ---------------------------------------------------------------------------
// Flash attention, split-K x2, 32x32x16 MFMA, frag-major K/V LDS, static max,
// K/V double-buffer (round-12 structure, 55us proven).
// Round 15: fA/fB mask addends staged to LDS with K/V (T14) — removes the
// per-tile exposed ~200cy L2 latency of the global cinit loads.
// ---------------------------------------------------------------------------
__global__ __launch_bounds__(256, 3) void attn_split(
    const u16* __restrict__ Q, const u16* __restrict__ K,
    const u16* __restrict__ Vt, const float* __restrict__ fAg,
    const float* __restrict__ fBg, const int* __restrict__ gmask,
    u16* __restrict__ O0, u16* __restrict__ O1, float* __restrict__ Lp)
{
    __shared__ __align__(16) u16 KsA[8*64*8], VsA[8*64*8];
    __shared__ __align__(16) u16 KsB[8*64*8], VsB[8*64*8];
    __shared__ __align__(16) u16 Ps[4*2048];   // per-wave 4KB
    __shared__ __align__(16) float fLs[2][128]; // [buf][0:64]=fA, [64:128]=fB

    const int tid = threadIdx.x;
    const int w   = tid >> 6;
    const int l   = tid & 63;
    const int hi  = l >> 5;
    const int ln31 = l & 31;

    // XCD swizzle: 768 = 8 * 96 (bijective)
    const int bid = blockIdx.x;
    const int swz = (bid & 7) * 96 + (bid >> 3);
    const int half = swz & 1;
    const int q0  = ((swz >> 1) & 15) * 128;
    const int hb  = swz >> 5;
    const int h   = hb % NH;
    const int b   = hb / NH;
    const size_t bh = ((size_t)b*NH + h) * S_LEN;

    const int q_glob = q0 + 32*w + ln31;

    short8v aq[4];
    {
        const u16* qp = Q + (bh + q_glob)*HD + 8*hi;
        aq[0] = *(const short8v*)(qp);
        aq[1] = *(const short8v*)(qp + 16);
        aq[2] = *(const short8v*)(qp + 32);
        aq[3] = *(const short8v*)(qp + 48);
    }
    const int gq = gmask[(size_t)b*S_LEN + q_glob];
    const float* fAb_ = fAg + (size_t)b*S_LEN;
    const float* fBb_ = fBg + (size_t)b*S_LEN;

    float l_i = 0.f;
    f32x16 oa0, oa1;
    #pragma unroll
    for (int i = 0; i < 16; i++) { oa0[i] = 0.f; oa1[i] = 0.f; }

    const int str = tid >> 2;
    const int stc = tid & 3;
    const int wbase = ((str >> 5)*4 + stc)*512 + (str & 31)*8;
    const u16* Kbase = K + bh * HD;
    const u16* Vbase = Vt + (size_t)(b*NH + h) * HD * S_LEN;
    char* Pb = (char*)(Ps + w*2048);

    uint4 rk0, rk1, rv0, rv1;
    float4 rfl;

#define STAGE_REGS(KT) do {                                                   \
    const int kk0_ = (KT) * 64;                                               \
    const u16* kp_ = Kbase + (size_t)(kk0_ + str)*HD + stc*16;                \
    rk0 = *(const uint4*)(kp_); rk1 = *(const uint4*)(kp_ + 8);               \
    const u16* vp_ = Vbase + (size_t)str*S_LEN + kk0_ + stc*16;               \
    rv0 = *(const uint4*)(vp_); rv1 = *(const uint4*)(vp_ + 8);               \
    if (tid < 32)                                                             \
        rfl = *(const float4*)((tid < 16 ? fAb_ : fBb_) + kk0_ + (tid & 15)*4);\
} while(0)

#define WRITE_LDS(KS, VS, FL) do {                                           \
    *(uint4*)((KS) + wbase)       = rk0;                                      \
    *(uint4*)((KS) + wbase + 256) = rk1;                                      \
    *(uint4*)((VS) + wbase)       = rv0;                                      \
    *(uint4*)((VS) + wbase + 256) = rv1;                                      \
    if (tid < 32)                                                             \
        *(float4*)&(FL)[(tid >> 4)*64 + (tid & 15)*4] = rfl;                  \
} while(0)

#define COMPUTE(KS, VS, FL, K0) do {                                          \
    const float* fA_l = (FL);                                                 \
    const float* fB_l = (FL) + 64;                                            \
    const float* fP_l = gq ? fA_l : fB_l;                                     \
    f32x16 s0, s1;                                                            \
    const int diff_ = (K0) - q0;                                              \
    if (diff_ == 0 || diff_ == 64) {                                          \
        cinit_uni(s0, fA_l + 4*hi);                                           \
        cinit_uni(s1, fA_l + 32 + 4*hi);                                      \
    } else if (diff_ >= 256 || diff_ <= -192) {                               \
        cinit_uni(s0, fP_l + 4*hi);                                           \
        cinit_uni(s1, fP_l + 32 + 4*hi);                                      \
    } else {                                                                  \
        cinit_mixed(s0, fA_l + 4*hi, fB_l + 4*hi,                             \
                    q_glob - ((K0) + 4*hi), gq);                              \
        cinit_mixed(s1, fA_l + 32 + 4*hi, fB_l + 32 + 4*hi,                   \
                    q_glob - ((K0) + 32 + 4*hi), gq);                         \
    }                                                                         \
    __builtin_amdgcn_s_setprio(1);                                            \
    _Pragma("unroll")                                                         \
    for (int dd = 0; dd < 4; dd++) {                                          \
        short8v ak0 = *(const short8v*)((KS) + dd*512 + l*8);                 \
        short8v ak1 = *(const short8v*)((KS) + (4+dd)*512 + l*8);             \
        s0 = __builtin_amdgcn_mfma_f32_32x32x16_bf16(ak0, aq[dd], s0, 0,0,0); \
        s1 = __builtin_amdgcn_mfma_f32_32x32x16_bf16(ak1, aq[dd], s1, 0,0,0); \
    }                                                                         \
    __builtin_amdgcn_s_setprio(0);                                            \
    _Pragma("unroll")                                                         \
    for (int i = 0; i < 16; i++) {                                            \
        s0[i] = exp2_fast(s0[i]);                                             \
        s1[i] = exp2_fast(s1[i]);                                             \
    }                                                                         \
    {                                                                         \
        float a0 = (s0[0]+s0[1]) + (s0[2]+s0[3]);                             \
        float a1 = (s0[4]+s0[5]) + (s0[6]+s0[7]);                             \
        float a2 = (s0[8]+s0[9]) + (s0[10]+s0[11]);                           \
        float a3 = (s0[12]+s0[13]) + (s0[14]+s0[15]);                         \
        float b0 = (s1[0]+s1[1]) + (s1[2]+s1[3]);                             \
        float b1 = (s1[4]+s1[5]) + (s1[6]+s1[7]);                             \
        float b2 = (s1[8]+s1[9]) + (s1[10]+s1[11]);                           \
        float b3 = (s1[12]+s1[13]) + (s1[14]+s1[15]);                         \
        l_i += ((a0+a1)+(a2+a3)) + ((b0+b1)+(b2+b3));                         \
    }                                                                         \
    _Pragma("unroll")                                                         \
    for (int g = 0; g < 4; g++) {                                             \
        uint2 v0, v1;                                                         \
        v0.x = pk2bf(s0[4*g+0], s0[4*g+1]);                                   \
        v0.y = pk2bf(s0[4*g+2], s0[4*g+3]);                                   \
        v1.x = pk2bf(s1[4*g+0], s1[4*g+1]);                                   \
        v1.y = pk2bf(s1[4*g+2], s1[4*g+3]);                                   \
        const int g0_ = g, g1_ = g + 4;                                       \
        *(uint2*)(Pb + (g0_>>1)*1024 + (((g0_&1)<<5) | ln31)*16 + hi*8) = v0; \
        *(uint2*)(Pb + (g1_>>1)*1024 + (((g1_&1)<<5) | ln31)*16 + hi*8) = v1; \
    }                                                                         \
    __builtin_amdgcn_s_setprio(1);                                            \
    _Pragma("unroll")                                                         \
    for (int c = 0; c < 4; c++) {                                             \
        short8v pb  = *(const short8v*)(Pb + c*1024 + l*16);                  \
        short8v av0 = *(const short8v*)((VS) + c*512 + l*8);                  \
        short8v av1 = *(const short8v*)((VS) + (4+c)*512 + l*8);              \
        oa0 = __builtin_amdgcn_mfma_f32_32x32x16_bf16(av0, pb, oa0, 0,0,0);   \
        oa1 = __builtin_amdgcn_mfma_f32_32x32x16_bf16(av1, pb, oa1, 0,0,0);   \
    }                                                                         \
    __builtin_amdgcn_s_setprio(0);                                            \
} while(0)

    const int t0 = half * 16, t1 = t0 + 16;
    STAGE_REGS(t0);
    WRITE_LDS(KsA, VsA, fLs[0]);
    __syncthreads();

    // ONE barrier per tile (dbuf): WRITE(other) is disjoint from COMPUTE(cur);
    // every wave's prior COMPUTE(other) precedes the last barrier.
    for (int kt = t0; kt < t1; kt += 2) {
        STAGE_REGS(kt+1);
        COMPUTE(KsA, VsA, fLs[0], kt*64);
        WRITE_LDS(KsB, VsB, fLs[1]);
        __syncthreads();
        {
            const int kn = (kt+2 < t1) ? (kt+2) : (t1-1);
            STAGE_REGS(kn);
        }
        COMPUTE(KsB, VsB, fLs[1], (kt+1)*64);
        WRITE_LDS(KsA, VsA, fLs[0]);
        __syncthreads();
    }

#undef STAGE_REGS
#undef WRITE_LDS
#undef COMPUTE

    // epilogue: combine l across hi-halves once; write unnormalized O + l.
    l_i += __shfl_xor(l_i, 32);
    {
        u16* op = (half ? O1 : O0) + (bh + q_glob)*HD + 4*hi;
        #pragma unroll
        for (int m = 0; m < 4; m++) {
            *(unsigned*)(op + 8*m)          = pk2bf(oa0[4*m],   oa0[4*m+1]);
            *(unsigned*)(op + 8*m + 2)      = pk2bf(oa0[4*m+2], oa0[4*m+3]);
            *(unsigned*)(op + 32 + 8*m)     = pk2bf(oa1[4*m],   oa1[4*m+1]);
            *(unsigned*)(op + 32 + 8*m + 2) = pk2bf(oa1[4*m+2], oa1[4*m+3]);
        }
        if (l < 32) Lp[half*NROW + bh + q_glob] = l_i;
    }
}

// ---------------------------------------------------------------------------
// Merge split-K halves: same static scale on both -> O = (O0+O1)/(l0+l1).
// ---------------------------------------------------------------------------
__global__ __launch_bounds__(256) void attn_merge(
    const u16* __restrict__ O0, const u16* __restrict__ O1,
    const float* __restrict__ Lp, u16* __restrict__ AO)
{
    const int idx8 = (blockIdx.x*256 + threadIdx.x) * 8;   // (B,S,H) offset
    const int b   = idx8 / (S_LEN*HID);
    const int rem = idx8 - b*(S_LEN*HID);
    const int s   = rem / HID;
    const int hd  = rem - s*HID;
    const int hh  = hd >> 6;
    const int d0  = hd & 63;
    const int row = (b*NH + hh)*S_LEN + s;

    const float inv = 1.f / (Lp[row] + Lp[NROW + row]);

    const size_t ioff = (size_t)row*HD + d0;
    uint4 a = *(const uint4*)(O0 + ioff);
    uint4 c = *(const uint4*)(O1 + ioff);
    const u16* ap = (const u16*)&a;
    const u16* cp = (const u16*)&c;
    unsigned ow[4];
    #pragma unroll
    for (int j = 0; j < 4; j++) {
        float f0 = (bf2f(ap[2*j])   + bf2f(cp[2*j]))   * inv;
        float f1 = (bf2f(ap[2*j+1]) + bf2f(cp[2*j+1])) * inv;
        ow[j] = pk2bf(f0, f1);
    }
    uint4 o; o.x=ow[0]; o.y=ow[1]; o.z=ow[2]; o.w=ow[3];
    *(uint4*)(AO + idx8) = o;
}

// ---------------------------------------------------------------------------
extern "C" void kernel_launch(void* const* d_in, const int* in_sizes, int n_in,
                              void* d_out, int out_size, void* d_ws, size_t ws_size,
                              hipStream_t stream)
{
    const float* hidden = (const float*)d_in[0];
    const int*   amask  = (const int*)d_in[1];
    const int*   gmask  = (const int*)d_in[2];
    const float* Wq = (const float*)d_in[3];
    const float* bq = (const float*)d_in[4];
    const float* Wk = (const float*)d_in[5];
    const float* bk = (const float*)d_in[6];
    const float* Wv = (const float*)d_in[7];
    const float* bv = (const float*)d_in[8];
    const float* Wo = (const float*)d_in[9];
    const float* bo = (const float*)d_in[10];
    float* out = (float*)d_out;

    char* ws = (char*)d_ws;
    const size_t NTOK = (size_t)2 * S_LEN * HID;   // 3,145,728
    u16* hbf   = (u16*)(ws);                       // hidden bf16; later O1 partial
    u16* w4    = (u16*)(ws + 6291456);             // Wq',Wk,Wv,Wo bf16
    float* Lp  = (float*)(ws + 6291456);           // overlays Wq' slice post-QKV
    u16* qkvbf = (u16*)(ws + 11010048);            // Q, K (2 x NTOK)
    float* fAg = (float*)(ws + 23592960);          // mask addends
    float* fBg = (float*)(ws + 23609344);
    u16* vtbf  = (u16*)(ws + 29884416);            // Vt; later merged AO (B,S,H)
    u16* aobf  = (u16*)(ws + 36175872);            // O0 partial

    convert_inputs<<<dim3(1536, 6), 256, 0, stream>>>(
        hidden, Wq, Wk, Wv, Wo, amask, gmask, hbf, w4, fAg, fBg);

    gemm_mfma<<<dim3(32, 6, 3), 256, 0, stream>>>(
        hbf, w4, bq, bk, bv, qkvbf, vtbf, nullptr, 0);

    u16* Qbf = qkvbf;
    u16* Kbf = qkvbf + NTOK;

    attn_split<<<dim3(768), 256, 0, stream>>>(Qbf, Kbf, vtbf, fAg, fBg, gmask,
                                              aobf, hbf, Lp);

    attn_merge<<<dim3(1536), 256, 0, stream>>>(aobf, hbf, Lp, vtbf);

    gemm_mfma<<<dim3(32, 6), 256, 0, stream>>>(
        vtbf, w4, bo, nullptr, nullptr, nullptr, nullptr, out, 1);
}